// Round 1
// 13821.272 us; speedup vs baseline: 1.2428x; 1.2428x over previous
//
#include <hip/hip_runtime.h>

// LSTM T=2048 B=32 DIN=512 H=512.
// Persistent 32-WG scan; weights resident in VGPRs as MFMA B-fragments.
// Cross-WG h exchange via LLC using targeted sc0/sc1 accesses (no L2
// invalidate / writeback fences), raw s_barrier + minimal explicit waitcnt.
// Output layout: [h (32*512) | c (32*512) | outs (2048*32*512)] f32.

#define TT 2048
#define BB 32
#define HH 512
#define NWG 32

typedef __attribute__((ext_vector_type(8))) short short8;
typedef __attribute__((ext_vector_type(4))) float fv4;
typedef __attribute__((ext_vector_type(2))) float fv2;
typedef __attribute__((ext_vector_type(4))) unsigned short usv4;

__device__ __forceinline__ unsigned short f2bf(float f) {
  unsigned u = __builtin_bit_cast(unsigned, f);
  u += 0x7fffu + ((u >> 16) & 1u);   // RNE (inputs finite)
  return (unsigned short)(u >> 16);
}
__device__ __forceinline__ float sigm(float x) { return 1.f / (1.f + __expf(-x)); }
__device__ __forceinline__ float tanhfast(float x) { return 1.f - 2.f / (__expf(2.f * x) + 1.f); }

// ---- prologue: pack transposed bf16 weights, summed bias, h(0), flags ----
__global__ void pack_kernel(
    const float* __restrict__ h0,
    const float* __restrict__ Wii, const float* __restrict__ bii,
    const float* __restrict__ Whi, const float* __restrict__ bhi,
    const float* __restrict__ Wif, const float* __restrict__ bif,
    const float* __restrict__ Whf, const float* __restrict__ bhf,
    const float* __restrict__ Wig, const float* __restrict__ big,
    const float* __restrict__ Whg, const float* __restrict__ bhg,
    const float* __restrict__ Wio, const float* __restrict__ bio,
    const float* __restrict__ Who, const float* __restrict__ bho,
    unsigned short* __restrict__ WhT, unsigned short* __restrict__ WxT,
    float* __restrict__ bsum, unsigned short* __restrict__ hbuf,
    int* __restrict__ flags)
{
  int idx = blockIdx.x * 256 + threadIdx.x;
  if (idx < 2048 * 512) {                 // WhT/WxT: row r = gate*512+unit, col k
    int r = idx >> 9, k = idx & 511;
    int g = r >> 9, j = r & 511;
    const float* Wh_ = (g == 0) ? Whi : (g == 1) ? Whf : (g == 2) ? Whg : Who;
    const float* Wx_ = (g == 0) ? Wii : (g == 1) ? Wif : (g == 2) ? Wig : Wio;
    WhT[idx] = f2bf(Wh_[k * 512 + j]);
    WxT[idx] = f2bf(Wx_[k * 512 + j]);
  } else {
    int r2 = idx - 2048 * 512;
    if (r2 < 2048) {
      int g = r2 >> 9, j = r2 & 511;
      const float* bi_ = (g == 0) ? bii : (g == 1) ? bif : (g == 2) ? big : bio;
      const float* bh_ = (g == 0) ? bhi : (g == 1) ? bhf : (g == 2) ? bhg : bho;
      bsum[r2] = bi_[j] + bh_[j];
    } else if (r2 < 2048 + 16384) {
      int m = r2 - 2048;
      hbuf[m] = f2bf(h0[m]);              // parity-0 h buffer = h(0)
    } else if (r2 < 2048 + 16384 + NWG) {
      flags[r2 - 2048 - 16384] = 0;       // flags[w]=s  <=>  h(s) slice written
    }
  }
}

// ---- persistent scan ----
__global__ __launch_bounds__(256, 1) void lstm_scan(
    const float* __restrict__ xs, const float* __restrict__ c0,
    const unsigned short* __restrict__ WhT, const unsigned short* __restrict__ WxT,
    const float* __restrict__ bsum,
    unsigned short* __restrict__ hbuf, int* __restrict__ flags,
    float* __restrict__ out)
{
  __shared__ unsigned short xt[BB][520];  // x_t bf16, pad 8 (rows 16B-aligned)
  __shared__ float gl[4][BB][18];         // gate preacts exchange, pad 18 (<=2-way banks)

  const int tid = threadIdx.x;
  const int w = tid >> 6;                 // wave = gate (i,f,g,o)
  const int lane = tid & 63;
  const int n = lane & 15;                // MFMA n / A-row m
  const int q = lane >> 4;                // quad
  const int wg = blockIdx.x;
  const int j0 = wg * 16;                 // owned hidden-unit slice

  // B-fragments resident in VGPRs for all 2048 steps (64+64 VGPRs/lane).
  short8 whf[16], wxf[16];
  {
    const unsigned base = (unsigned)(w * 512 + j0 + n) * 512u + (unsigned)q * 8u;
#pragma unroll
    for (int kc = 0; kc < 16; ++kc) {
      whf[kc] = *(const short8*)(WhT + base + kc * 32);
      wxf[kc] = *(const short8*)(WxT + base + kc * 32);
    }
  }

  // elementwise ownership: thread -> (b, jl), units jl, jl+1 (jl even)
  const int bE = (2 * tid) >> 4;
  const int jlE = (2 * tid) & 15;
  float c_st[2], hv[2], bias0[2], bias1[2], bias2[2], bias3[2];
#pragma unroll
  for (int e = 0; e < 2; ++e) {
    c_st[e] = c0[bE * HH + j0 + jlE + e];
    bias0[e] = bsum[0 * 512 + j0 + jlE + e];
    bias1[e] = bsum[1 * 512 + j0 + jlE + e];
    bias2[e] = bsum[2 * 512 + j0 + jlE + e];
    bias3[e] = bsum[3 * 512 + j0 + jlE + e];
    hv[e] = 0.f;
  }

  // stage x(0): coalesced f32 loads -> bf16 -> LDS
#pragma unroll
  for (int i = 0; i < 16; ++i) {
    int f = i * 1024 + tid * 4;
    fv4 v = *(const fv4*)(xs + f);
    int r = f >> 9, cc = f & 511;
    usv4 bv = { f2bf(v[0]), f2bf(v[1]), f2bf(v[2]), f2bf(v[3]) };
    *(usv4*)&xt[r][cc] = bv;
  }

#pragma unroll 1
  for (int t = 0; t < TT; ++t) {
    // ---- wait for h(t) from all WGs (direct-LLC poll, no cache fences) ----
    if (tid < NWG) {
      const int* fp = flags + tid;
      for (;;) {
        int v;
        asm volatile("global_load_dword %0, %1, off sc0 sc1\n\t"
                     "s_waitcnt vmcnt(0)"
                     : "=v"(v) : "v"(fp) : "memory");
        if (v >= t) break;
        __builtin_amdgcn_s_sleep(1);
      }
    }
    // B_top: xt/gl LDS handoff needs only lgkmcnt; NO vmem drain, NO L2 inv.
    asm volatile("s_waitcnt lgkmcnt(0)" ::: "memory");
    asm volatile("s_barrier" ::: "memory");

    // ---- issue ALL h A-fragment loads up front (coherent LLC reads) ----
    const unsigned short* hb = hbuf + (t & 1) * (BB * HH);
    const unsigned short* hrow0 = hb + n * HH + q * 8;
    const unsigned short* hrow1 = hb + (16 + n) * HH + q * 8;
    short8 ha0[16], ha1[16];
#pragma unroll
    for (int kc = 0; kc < 16; ++kc) {
      asm volatile("global_load_dwordx4 %0, %2, off offset:%4 sc0 sc1\n\t"
                   "global_load_dwordx4 %1, %3, off offset:%4 sc0 sc1"
                   : "=v"(ha0[kc]), "=v"(ha1[kc])
                   : "v"(hrow0), "v"(hrow1), "n"(kc * 64)
                   : "memory");
    }

    // ---- x-side MFMAs from LDS hide the h-load LLC latency ----
    fv4 acc0 = {0.f, 0.f, 0.f, 0.f};   // batch rows 0..15
    fv4 acc1 = {0.f, 0.f, 0.f, 0.f};   // batch rows 16..31
#pragma unroll
    for (int kc = 0; kc < 16; ++kc) {
      short8 a0 = *(const short8*)&xt[n][kc * 32 + q * 8];
      short8 a1 = *(const short8*)&xt[16 + n][kc * 32 + q * 8];
      acc0 = __builtin_amdgcn_mfma_f32_16x16x32_bf16(a0, wxf[kc], acc0, 0, 0, 0);
      acc1 = __builtin_amdgcn_mfma_f32_16x16x32_bf16(a1, wxf[kc], acc1, 0, 0, 0);
    }
    // single wait for the 32 h loads; sched_barrier stops MFMA hoisting (rule 18)
    asm volatile("s_waitcnt vmcnt(0)" ::: "memory");
    __builtin_amdgcn_sched_barrier(0);
#pragma unroll
    for (int kc = 0; kc < 16; ++kc) {
      acc0 = __builtin_amdgcn_mfma_f32_16x16x32_bf16(ha0[kc], whf[kc], acc0, 0, 0, 0);
      acc1 = __builtin_amdgcn_mfma_f32_16x16x32_bf16(ha1[kc], whf[kc], acc1, 0, 0, 0);
    }

    // ---- exchange gate preacts: D layout col=lane&15, row=quad*4+reg ----
#pragma unroll
    for (int r = 0; r < 4; ++r) {
      gl[w][q * 4 + r][n] = acc0[r];
      gl[w][16 + q * 4 + r][n] = acc1[r];
    }
    asm volatile("s_waitcnt lgkmcnt(0)" ::: "memory");
    asm volatile("s_barrier" ::: "memory");

    // ---- elementwise LSTM cell, c in registers; h store direct-to-LLC ----
    float oo0, oo1;
    {
      fv2 gi = *(const fv2*)&gl[0][bE][jlE];
      fv2 gf = *(const fv2*)&gl[1][bE][jlE];
      fv2 gg = *(const fv2*)&gl[2][bE][jlE];
      fv2 go = *(const fv2*)&gl[3][bE][jlE];
      float oo[2];
#pragma unroll
      for (int e = 0; e < 2; ++e) {
        float ig = sigm(gi[e] + bias0[e]);
        float fg = sigm(gf[e] + bias1[e]);
        float gv = tanhfast(gg[e] + bias2[e]);
        float og = sigm(go[e] + bias3[e]);
        float cn = fg * c_st[e] + ig * gv;
        c_st[e] = cn;
        hv[e] = og * tanhfast(cn);
        oo[e] = og;
      }
      oo0 = oo[0]; oo1 = oo[1];
      unsigned hp = (unsigned)f2bf(hv[0]) | ((unsigned)f2bf(hv[1]) << 16);
      const unsigned short* hdst =
          hbuf + ((t + 1) & 1) * (BB * HH) + bE * HH + j0 + jlE;
      asm volatile("global_store_dword %0, %1, off sc0 sc1"
                   :: "v"(hdst), "v"(hp) : "memory");
    }
    // drain h stores to LLC, then barrier, then release flag (no wbl2!)
    asm volatile("s_waitcnt vmcnt(0)" ::: "memory");
    asm volatile("s_barrier" ::: "memory");
    if (tid == 0) {
      int fvv = t + 1;
      asm volatile("global_store_dword %0, %1, off sc0 sc1"
                   :: "v"(flags + wg), "v"(fvv) : "memory");
    }

    // out store: cached, off the release path
    {
      fv2 ov = {oo0, oo1};
      *(fv2*)(out + 32768 + (size_t)t * 16384 + bE * 512 + j0 + jlE) = ov;
    }

    // ---- prefetch/stage x(t+1) while others catch up (L2 stays warm now) ----
    if (t + 1 < TT) {
      const float* xsrc = xs + (size_t)(t + 1) * 16384;
#pragma unroll
      for (int i = 0; i < 16; ++i) {
        int f = i * 1024 + tid * 4;
        fv4 v = *(const fv4*)(xsrc + f);
        int r = f >> 9, cc = f & 511;
        usv4 bv = { f2bf(v[0]), f2bf(v[1]), f2bf(v[2]), f2bf(v[3]) };
        *(usv4*)&xt[r][cc] = bv;
      }
    }
  }

  // final h, c (f32)
  {
    fv2 hvv = {hv[0], hv[1]};
    fv2 cvv = {c_st[0], c_st[1]};
    *(fv2*)(out + bE * 512 + j0 + jlE) = hvv;
    *(fv2*)(out + 16384 + bE * 512 + j0 + jlE) = cvv;
  }
}

extern "C" void kernel_launch(void* const* d_in, const int* in_sizes, int n_in,
                              void* d_out, int out_size, void* d_ws, size_t ws_size,
                              hipStream_t stream) {
  (void)in_sizes; (void)n_in; (void)out_size;
  const float* h0  = (const float*)d_in[0];
  const float* c0  = (const float*)d_in[1];
  const float* xs  = (const float*)d_in[2];
  const float* Wii = (const float*)d_in[3];
  const float* bii = (const float*)d_in[4];
  const float* Whi = (const float*)d_in[5];
  const float* bhi = (const float*)d_in[6];
  const float* Wif = (const float*)d_in[7];
  const float* bif = (const float*)d_in[8];
  const float* Whf = (const float*)d_in[9];
  const float* bhf = (const float*)d_in[10];
  const float* Wig = (const float*)d_in[11];
  const float* big = (const float*)d_in[12];
  const float* Whg = (const float*)d_in[13];
  const float* bhg = (const float*)d_in[14];
  const float* Wio = (const float*)d_in[15];
  const float* bio = (const float*)d_in[16];
  const float* Who = (const float*)d_in[17];
  const float* bho = (const float*)d_in[18];

  // ws layout: WhT 2MB | WxT 2MB | bsum 8KB | hbuf 64KB | flags 128B  (~4.27MB)
  char* ws = (char*)d_ws;
  unsigned short* WhT  = (unsigned short*)ws;
  unsigned short* WxT  = (unsigned short*)(ws + (2u << 20));
  float*          bsum = (float*)(ws + (4u << 20));
  unsigned short* hbuf = (unsigned short*)(ws + (4u << 20) + 8192);
  int*            flags = (int*)(ws + (4u << 20) + 8192 + 65536);
  if (ws_size < (4u << 20) + 8192 + 65536 + 128) return;  // visible failure if ws too small

  const int total = 2048 * 512 + 2048 + 16384 + NWG;
  pack_kernel<<<(total + 255) / 256, 256, 0, stream>>>(
      h0, Wii, bii, Whi, bhi, Wif, bif, Whf, bhf,
      Wig, big, Whg, bhg, Wio, bio, Who, bho,
      WhT, WxT, bsum, hbuf, flags);
  lstm_scan<<<NWG, 256, 0, stream>>>(xs, c0, WhT, WxT, bsum, hbuf, flags, (float*)d_out);
}

// Round 3
// 10830.691 us; speedup vs baseline: 1.5860x; 1.2761x over previous
//
#include <hip/hip_runtime.h>

// LSTM T=2048 B=32 DIN=512 H=512.
// Persistent 32-WG scan; weights resident in VGPRs as MFMA B-fragments.
// Device-scope (sc0 sc1) h/flag exchange via LLC (round-1 proven protocol).
// New: cooperative h staging into LDS (1 LLC round trip/step, counted vmcnt),
// x(t+2) register prefetch via asm loads, convert-to-LDS in sync slack (T14).
// Output layout: [h (32*512) | c (32*512) | outs (2048*32*512)] f32.

#define TT 2048
#define BB 32
#define HH 512
#define NWG 32

typedef __attribute__((ext_vector_type(8))) short short8;
typedef __attribute__((ext_vector_type(4))) float fv4;
typedef __attribute__((ext_vector_type(2))) float fv2;
typedef __attribute__((ext_vector_type(4))) unsigned short usv4;
typedef __attribute__((ext_vector_type(4))) int iv4;

__device__ __forceinline__ unsigned short f2bf(float f) {
  unsigned u = __builtin_bit_cast(unsigned, f);
  u += 0x7fffu + ((u >> 16) & 1u);   // RNE (inputs finite)
  return (unsigned short)(u >> 16);
}
__device__ __forceinline__ float sigm(float x) { return 1.f / (1.f + __expf(-x)); }
__device__ __forceinline__ float tanhfast(float x) { return 1.f - 2.f / (__expf(2.f * x) + 1.f); }

// ---- prologue: pack transposed bf16 weights, summed bias, h(0), flags ----
__global__ void pack_kernel(
    const float* __restrict__ h0,
    const float* __restrict__ Wii, const float* __restrict__ bii,
    const float* __restrict__ Whi, const float* __restrict__ bhi,
    const float* __restrict__ Wif, const float* __restrict__ bif,
    const float* __restrict__ Whf, const float* __restrict__ bhf,
    const float* __restrict__ Wig, const float* __restrict__ big,
    const float* __restrict__ Whg, const float* __restrict__ bhg,
    const float* __restrict__ Wio, const float* __restrict__ bio,
    const float* __restrict__ Who, const float* __restrict__ bho,
    unsigned short* __restrict__ WhT, unsigned short* __restrict__ WxT,
    float* __restrict__ bsum, unsigned short* __restrict__ hbuf,
    int* __restrict__ flags)
{
  int idx = blockIdx.x * 256 + threadIdx.x;
  if (idx < 2048 * 512) {                 // WhT/WxT: row r = gate*512+unit, col k
    int r = idx >> 9, k = idx & 511;
    int g = r >> 9, j = r & 511;
    const float* Wh_ = (g == 0) ? Whi : (g == 1) ? Whf : (g == 2) ? Whg : Who;
    const float* Wx_ = (g == 0) ? Wii : (g == 1) ? Wif : (g == 2) ? Wig : Wio;
    WhT[idx] = f2bf(Wh_[k * 512 + j]);
    WxT[idx] = f2bf(Wx_[k * 512 + j]);
  } else {
    int r2 = idx - 2048 * 512;
    if (r2 < 2048) {
      int g = r2 >> 9, j = r2 & 511;
      const float* bi_ = (g == 0) ? bii : (g == 1) ? bif : (g == 2) ? big : bio;
      const float* bh_ = (g == 0) ? bhi : (g == 1) ? bhf : (g == 2) ? bhg : bho;
      bsum[r2] = bi_[j] + bh_[j];
    } else if (r2 < 2048 + 16384) {
      int m = r2 - 2048;
      hbuf[m] = f2bf(h0[m]);              // parity-0 h buffer = h(0)
    } else if (r2 < 2048 + 16384 + NWG) {
      flags[r2 - 2048 - 16384] = 0;       // flags[w]=s  <=>  h(s) slice written
    }
  }
}

// ---- persistent scan ----
__global__ __launch_bounds__(256, 1) void lstm_scan(
    const float* __restrict__ xs, const float* __restrict__ c0,
    const unsigned short* __restrict__ WhT, const unsigned short* __restrict__ WxT,
    const float* __restrict__ bsum,
    unsigned short* __restrict__ hbuf, int* __restrict__ flags,
    float* __restrict__ out)
{
  __shared__ unsigned short xt[2][BB][520];  // x bf16 ring, pad 8 (rows 16B-aligned)
  __shared__ unsigned short hl[BB][520];     // staged h(t) tile
  __shared__ float gl[4][BB][18];            // gate preacts exchange

  const int tid = threadIdx.x;
  const int w = tid >> 6;                 // wave = gate (i,f,g,o)
  const int lane = tid & 63;
  const int n = lane & 15;                // MFMA n / A-row m
  const int q = lane >> 4;                // quad
  const int wg = blockIdx.x;
  const int j0 = wg * 16;                 // owned hidden-unit slice

  // B-fragments resident in VGPRs for all 2048 steps (64+64 VGPRs/lane).
  short8 whf[16], wxf[16];
  {
    const unsigned base = (unsigned)(w * 512 + j0 + n) * 512u + (unsigned)q * 8u;
#pragma unroll
    for (int kc = 0; kc < 16; ++kc) {
      whf[kc] = *(const short8*)(WhT + base + kc * 32);
      wxf[kc] = *(const short8*)(WxT + base + kc * 32);
    }
  }

  // elementwise ownership: thread -> (b, jl), units jl, jl+1 (jl even)
  const int bE = (2 * tid) >> 4;
  const int jlE = (2 * tid) & 15;
  float c_st[2], hv[2], bias0[2], bias1[2], bias2[2], bias3[2];
#pragma unroll
  for (int e = 0; e < 2; ++e) {
    c_st[e] = c0[bE * HH + j0 + jlE + e];
    bias0[e] = bsum[0 * 512 + j0 + jlE + e];
    bias1[e] = bsum[1 * 512 + j0 + jlE + e];
    bias2[e] = bsum[2 * 512 + j0 + jlE + e];
    bias3[e] = bsum[3 * 512 + j0 + jlE + e];
    hv[e] = 0.f;
  }

  // stage x(0) -> xt[0]; prefetch x(1) into registers
#pragma unroll
  for (int i = 0; i < 16; ++i) {
    int f = i * 1024 + tid * 4;
    fv4 v = *(const fv4*)(xs + f);
    int r = f >> 9, cc = f & 511;
    usv4 bv = { f2bf(v[0]), f2bf(v[1]), f2bf(v[2]), f2bf(v[3]) };
    *(usv4*)&xt[0][r][cc] = bv;
  }
  fv4 xv[16];
#pragma unroll
  for (int i = 0; i < 16; ++i)
    xv[i] = *(const fv4*)(xs + 16384 + i * 1024 + tid * 4);
  __syncthreads();

#pragma unroll 1
  for (int t = 0; t < TT; ++t) {
    const int cur = t & 1, nxt = cur ^ 1;

    // 1. convert xv (= x(t+1)) -> xt[nxt]  (local work, hidden in sync slack)
    if (t + 1 < TT) {
#pragma unroll
      for (int i = 0; i < 16; ++i) {
        int f = i * 1024 + tid * 4;
        int r = f >> 9, cc = f & 511;
        usv4 bv = { f2bf(xv[i][0]), f2bf(xv[i][1]), f2bf(xv[i][2]), f2bf(xv[i][3]) };
        *(usv4*)&xt[nxt][r][cc] = bv;
      }
    }

    // 2. wait for h(t): every wave polls all 32 flags (one cacheline/wave);
    //    embedded vmcnt(0) also drains this thread's stores/prefetches.
    {
      const int* fp = flags + (lane & 31);
      int v;
      do {
        asm volatile("global_load_dword %0, %1, off sc0 sc1\n\ts_waitcnt vmcnt(0)"
                     : "=v"(v) : "v"(fp) : "memory");
      } while (v < t);
    }

    // 3. cooperative h staging loads: 8 x dwordx4/thread = 32KB/WG, one round
    const unsigned short* hb = hbuf + cur * (BB * HH);
    iv4 hreg[8];
#pragma unroll
    for (int rd = 0; rd < 8; ++rd) {
      asm volatile("global_load_dwordx4 %0, %1, off sc0 sc1"
                   : "=&v"(hreg[rd]) : "v"(hb + rd * 2048 + tid * 8) : "memory");
    }

    // 4. x(t+2) prefetch into registers (asm: count & order compiler-proof;
    //    clamped src keeps outstanding-op count at exactly 16)
    {
      const float* xsrc = xs + (size_t)((t + 2 < TT) ? (t + 2) : (TT - 1)) * 16384;
#pragma unroll
      for (int i = 0; i < 16; ++i) {
        asm volatile("global_load_dwordx4 %0, %1, off"
                     : "=&v"(xv[i]) : "v"(xsrc + i * 1024 + tid * 4) : "memory");
      }
    }

    // 5. x-side MFMAs from xt[cur] hide the h-load LLC latency
    fv4 acc0 = {0.f, 0.f, 0.f, 0.f};   // batch rows 0..15
    fv4 acc1 = {0.f, 0.f, 0.f, 0.f};   // batch rows 16..31
#pragma unroll
    for (int kc = 0; kc < 16; ++kc) {
      short8 a0 = *(const short8*)&xt[cur][n][kc * 32 + q * 8];
      short8 a1 = *(const short8*)&xt[cur][16 + n][kc * 32 + q * 8];
      acc0 = __builtin_amdgcn_mfma_f32_16x16x32_bf16(a0, wxf[kc], acc0, 0, 0, 0);
      acc1 = __builtin_amdgcn_mfma_f32_16x16x32_bf16(a1, wxf[kc], acc1, 0, 0, 0);
    }

    // 6. counted wait: 8 h loads are the oldest of 24 outstanding -> vmcnt(16)
    asm volatile("s_waitcnt vmcnt(16)" ::: "memory");
    __builtin_amdgcn_sched_barrier(0);
#pragma unroll
    for (int rd = 0; rd < 8; ++rd) {
      int f = rd * 2048 + tid * 8;
      int r = f >> 9, cc = f & 511;
      *(iv4*)&hl[r][cc] = hreg[rd];
    }
    asm volatile("s_waitcnt lgkmcnt(0)" ::: "memory");
    asm volatile("s_barrier" ::: "memory");

    // 7. h-side MFMAs from LDS
#pragma unroll
    for (int kc = 0; kc < 16; ++kc) {
      short8 a0 = *(const short8*)&hl[n][kc * 32 + q * 8];
      short8 a1 = *(const short8*)&hl[16 + n][kc * 32 + q * 8];
      acc0 = __builtin_amdgcn_mfma_f32_16x16x32_bf16(a0, whf[kc], acc0, 0, 0, 0);
      acc1 = __builtin_amdgcn_mfma_f32_16x16x32_bf16(a1, whf[kc], acc1, 0, 0, 0);
    }

    // 8. exchange gate preacts: D layout col=lane&15, row=quad*4+reg
#pragma unroll
    for (int r = 0; r < 4; ++r) {
      gl[w][q * 4 + r][n] = acc0[r];
      gl[w][16 + q * 4 + r][n] = acc1[r];
    }
    asm volatile("s_waitcnt lgkmcnt(0)" ::: "memory");
    asm volatile("s_barrier" ::: "memory");

    // 9. elementwise LSTM cell; h store direct-to-LLC
    float oo0, oo1;
    {
      fv2 gi = *(const fv2*)&gl[0][bE][jlE];
      fv2 gf = *(const fv2*)&gl[1][bE][jlE];
      fv2 gg = *(const fv2*)&gl[2][bE][jlE];
      fv2 go = *(const fv2*)&gl[3][bE][jlE];
      float oo[2];
#pragma unroll
      for (int e = 0; e < 2; ++e) {
        float ig = sigm(gi[e] + bias0[e]);
        float fg = sigm(gf[e] + bias1[e]);
        float gv = tanhfast(gg[e] + bias2[e]);
        float og = sigm(go[e] + bias3[e]);
        float cn = fg * c_st[e] + ig * gv;
        c_st[e] = cn;
        hv[e] = og * tanhfast(cn);
        oo[e] = og;
      }
      oo0 = oo[0]; oo1 = oo[1];
      unsigned hp = (unsigned)f2bf(hv[0]) | ((unsigned)f2bf(hv[1]) << 16);
      const unsigned short* hdst =
          hbuf + nxt * (BB * HH) + bE * HH + j0 + jlE;
      asm volatile("global_store_dword %0, %1, off sc0 sc1"
                   :: "v"(hdst), "v"(hp) : "memory");
    }

    // 10. drain h store (x prefetches are long done), barrier, release flag
    asm volatile("s_waitcnt vmcnt(0)" ::: "memory");
    asm volatile("s_barrier" ::: "memory");
    if (tid == 0) {
      int fvv = t + 1;
      asm volatile("global_store_dword %0, %1, off sc0 sc1"
                   :: "v"(flags + wg), "v"(fvv) : "memory");
    }

    // 11. out store: cached, off the release path (next poll's vmcnt(0) drains)
    {
      fv2 ov = {oo0, oo1};
      *(fv2*)(out + 32768 + (size_t)t * 16384 + bE * 512 + j0 + jlE) = ov;
    }
  }

  // final h, c (f32)
  {
    fv2 hvv = {hv[0], hv[1]};
    fv2 cvv = {c_st[0], c_st[1]};
    *(fv2*)(out + bE * 512 + j0 + jlE) = hvv;
    *(fv2*)(out + 16384 + bE * 512 + j0 + jlE) = cvv;
  }
}

extern "C" void kernel_launch(void* const* d_in, const int* in_sizes, int n_in,
                              void* d_out, int out_size, void* d_ws, size_t ws_size,
                              hipStream_t stream) {
  (void)in_sizes; (void)n_in; (void)out_size;
  const float* h0  = (const float*)d_in[0];
  const float* c0  = (const float*)d_in[1];
  const float* xs  = (const float*)d_in[2];
  const float* Wii = (const float*)d_in[3];
  const float* bii = (const float*)d_in[4];
  const float* Whi = (const float*)d_in[5];
  const float* bhi = (const float*)d_in[6];
  const float* Wif = (const float*)d_in[7];
  const float* bif = (const float*)d_in[8];
  const float* Whf = (const float*)d_in[9];
  const float* bhf = (const float*)d_in[10];
  const float* Wig = (const float*)d_in[11];
  const float* big = (const float*)d_in[12];
  const float* Whg = (const float*)d_in[13];
  const float* bhg = (const float*)d_in[14];
  const float* Wio = (const float*)d_in[15];
  const float* bio = (const float*)d_in[16];
  const float* Who = (const float*)d_in[17];
  const float* bho = (const float*)d_in[18];

  // ws layout: WhT 2MB | WxT 2MB | bsum 8KB | hbuf 64KB | flags 128B  (~4.27MB)
  char* ws = (char*)d_ws;
  unsigned short* WhT  = (unsigned short*)ws;
  unsigned short* WxT  = (unsigned short*)(ws + (2u << 20));
  float*          bsum = (float*)(ws + (4u << 20));
  unsigned short* hbuf = (unsigned short*)(ws + (4u << 20) + 8192);
  int*            flags = (int*)(ws + (4u << 20) + 8192 + 65536);
  if (ws_size < (4u << 20) + 8192 + 65536 + 128) return;  // visible failure if ws too small

  const int total = 2048 * 512 + 2048 + 16384 + NWG;
  pack_kernel<<<(total + 255) / 256, 256, 0, stream>>>(
      h0, Wii, bii, Whi, bhi, Wif, bif, Whf, bhf,
      Wig, big, Whg, bhg, Wio, bio, Who, bho,
      WhT, WxT, bsum, hbuf, flags);
  lstm_scan<<<NWG, 256, 0, stream>>>(xs, c0, WhT, WxT, bsum, hbuf, flags, (float*)d_out);
}

// Round 4
// 7915.472 us; speedup vs baseline: 2.1701x; 1.3683x over previous
//
#include <hip/hip_runtime.h>

// LSTM T=2048 B=32 DIN=512 H=512.
// Persistent 32-worker scan. Workers self-colocate on one XCD via a
// deadlock-free first-come rank claim (XCD0-biased); if all 32 land on one
// XCD, h/flag sync runs at L2 scope (sc0-only: L1 is write-through, sc0
// loads bypass L1), else the round-3-proven device-scope (sc0 sc1) path.
// x(t+2) prefetch issued after the flag release (off the drain path),
// v_cvt_pk_bf16_f32 converts, even/odd-K split MFMA chains.
// Output layout: [h (32*512) | c (32*512) | outs (2048*32*512)] f32.

#define TT 2048
#define BB 32
#define HH 512
#define NWG 32

typedef __attribute__((ext_vector_type(8))) short short8;
typedef __attribute__((ext_vector_type(4))) float fv4;
typedef __attribute__((ext_vector_type(2))) float fv2;
typedef __attribute__((ext_vector_type(2))) unsigned int uiv2;
typedef __attribute__((ext_vector_type(4))) unsigned short usv4;
typedef __attribute__((ext_vector_type(4))) int iv4;

__device__ __forceinline__ unsigned short f2bf(float f) {
  unsigned u = __builtin_bit_cast(unsigned, f);
  u += 0x7fffu + ((u >> 16) & 1u);   // RNE (inputs finite)
  return (unsigned short)(u >> 16);
}
__device__ __forceinline__ float sigm(float x) { return 1.f / (1.f + __expf(-x)); }
__device__ __forceinline__ float tanhfast(float x) { return 1.f - 2.f / (__expf(2.f * x) + 1.f); }

// ---- scoped memory helpers (L = true: XCD-local L2 scope; false: device) ----
template<bool L> __device__ __forceinline__ int ldflag(const int* p) {
  int v;
  if constexpr (L)
    asm volatile("global_load_dword %0, %1, off sc0\n\ts_waitcnt vmcnt(0)"
                 : "=v"(v) : "v"(p) : "memory");
  else
    asm volatile("global_load_dword %0, %1, off sc0 sc1\n\ts_waitcnt vmcnt(0)"
                 : "=v"(v) : "v"(p) : "memory");
  return v;
}
template<bool L> __device__ __forceinline__ iv4 ldx4(const unsigned short* p) {
  iv4 v;
  if constexpr (L)
    asm volatile("global_load_dwordx4 %0, %1, off sc0"
                 : "=&v"(v) : "v"(p) : "memory");
  else
    asm volatile("global_load_dwordx4 %0, %1, off sc0 sc1"
                 : "=&v"(v) : "v"(p) : "memory");
  return v;
}
template<bool L> __device__ __forceinline__ void st32(void* p, unsigned v) {
  if constexpr (L)
    asm volatile("global_store_dword %0, %1, off sc0" :: "v"(p), "v"(v) : "memory");
  else
    asm volatile("global_store_dword %0, %1, off sc0 sc1" :: "v"(p), "v"(v) : "memory");
}

// ---- prologue: pack transposed bf16 weights, summed bias, h(0), sync state ----
__global__ void pack_kernel(
    const float* __restrict__ h0,
    const float* __restrict__ Wii, const float* __restrict__ bii,
    const float* __restrict__ Whi, const float* __restrict__ bhi,
    const float* __restrict__ Wif, const float* __restrict__ bif,
    const float* __restrict__ Whf, const float* __restrict__ bhf,
    const float* __restrict__ Wig, const float* __restrict__ big,
    const float* __restrict__ Whg, const float* __restrict__ bhg,
    const float* __restrict__ Wio, const float* __restrict__ bio,
    const float* __restrict__ Who, const float* __restrict__ bho,
    unsigned short* __restrict__ WhT, unsigned short* __restrict__ WxT,
    float* __restrict__ bsum, unsigned short* __restrict__ hbuf,
    int* __restrict__ flags, int* __restrict__ rankctr, int* __restrict__ xcc_pub)
{
  int idx = blockIdx.x * 256 + threadIdx.x;
  if (idx < 2048 * 512) {                 // WhT/WxT: row r = gate*512+unit, col k
    int r = idx >> 9, k = idx & 511;
    int g = r >> 9, j = r & 511;
    const float* Wh_ = (g == 0) ? Whi : (g == 1) ? Whf : (g == 2) ? Whg : Who;
    const float* Wx_ = (g == 0) ? Wii : (g == 1) ? Wif : (g == 2) ? Wig : Wio;
    WhT[idx] = f2bf(Wh_[k * 512 + j]);
    WxT[idx] = f2bf(Wx_[k * 512 + j]);
  } else {
    int r2 = idx - 2048 * 512;
    if (r2 < 2048) {
      int g = r2 >> 9, j = r2 & 511;
      const float* bi_ = (g == 0) ? bii : (g == 1) ? bif : (g == 2) ? big : bio;
      const float* bh_ = (g == 0) ? bhi : (g == 1) ? bhf : (g == 2) ? bhg : bho;
      bsum[r2] = bi_[j] + bh_[j];
    } else if (r2 < 2048 + 16384) {
      int m = r2 - 2048;
      hbuf[m] = f2bf(h0[m]);              // parity-0 h buffer = h(0)
    } else if (r2 < 2048 + 16384 + NWG) {
      flags[r2 - 2048 - 16384] = 0;       // flags[w]=s  <=>  h(s) slice written
    } else if (r2 == 2048 + 16384 + NWG) {
      rankctr[0] = 0;
    } else if (r2 < 2048 + 16384 + NWG + 1 + 64) {
      xcc_pub[r2 - (2048 + 16384 + NWG + 1)] = -1;
    }
  }
}

// ---- the scan loop body, templated on coherence scope ----
template<bool L>
__device__ __forceinline__ void run_scan(
    int wg, int tid,
    const float* __restrict__ xs, const float* __restrict__ c0,
    const unsigned short* __restrict__ WhT, const unsigned short* __restrict__ WxT,
    const float* __restrict__ bsum, unsigned short* __restrict__ hbuf,
    int* __restrict__ flags, float* __restrict__ out,
    unsigned short (*xt)[BB][520], unsigned short (*hl)[520], float (*gl)[BB][18])
{
  const int w = tid >> 6;                 // wave = gate (i,f,g,o)
  const int lane = tid & 63;
  const int n = lane & 15;                // MFMA n / A-row m
  const int q = lane >> 4;                // quad
  const int j0 = wg * 16;                 // owned hidden-unit slice

  // B-fragments resident in VGPRs for all 2048 steps (64+64 VGPRs/lane).
  short8 whf[16], wxf[16];
  {
    const unsigned base = (unsigned)(w * 512 + j0 + n) * 512u + (unsigned)q * 8u;
#pragma unroll
    for (int kc = 0; kc < 16; ++kc) {
      whf[kc] = *(const short8*)(WhT + base + kc * 32);
      wxf[kc] = *(const short8*)(WxT + base + kc * 32);
    }
  }

  // elementwise ownership: thread -> (b, jl), units jl, jl+1 (jl even)
  const int bE = (2 * tid) >> 4;
  const int jlE = (2 * tid) & 15;
  float c_st[2], hv[2], bias0[2], bias1[2], bias2[2], bias3[2];
#pragma unroll
  for (int e = 0; e < 2; ++e) {
    c_st[e] = c0[bE * HH + j0 + jlE + e];
    bias0[e] = bsum[0 * 512 + j0 + jlE + e];
    bias1[e] = bsum[1 * 512 + j0 + jlE + e];
    bias2[e] = bsum[2 * 512 + j0 + jlE + e];
    bias3[e] = bsum[3 * 512 + j0 + jlE + e];
    hv[e] = 0.f;
  }

  // stage x(0) -> xt[0]; prefetch x(1) into registers (plain, compiler-waited)
#pragma unroll
  for (int i = 0; i < 16; ++i) {
    int f = i * 1024 + tid * 4;
    fv4 v = *(const fv4*)(xs + f);
    int r = f >> 9, cc = f & 511;
    usv4 bv = { f2bf(v[0]), f2bf(v[1]), f2bf(v[2]), f2bf(v[3]) };
    *(usv4*)&xt[0][r][cc] = bv;
  }
  fv4 xv[16];
#pragma unroll
  for (int i = 0; i < 16; ++i)
    xv[i] = *(const fv4*)(xs + 16384 + i * 1024 + tid * 4);
  __syncthreads();

#pragma unroll 1
  for (int t = 0; t < TT; ++t) {
    const int cur = t & 1, nxt = cur ^ 1;

    // P0: drain x prefetch (+ out store); convert xv=x(t+1) -> xt[nxt].
    // sched_barrier: cvt reads asm-loaded regs — must not hoist above waitcnt.
    asm volatile("s_waitcnt vmcnt(0)" ::: "memory");
    __builtin_amdgcn_sched_barrier(0);
    if (t + 1 < TT) {
#pragma unroll
      for (int i = 0; i < 16; ++i) {
        unsigned d0, d1;
        asm("v_cvt_pk_bf16_f32 %0, %1, %2" : "=v"(d0) : "v"(xv[i][0]), "v"(xv[i][1]));
        asm("v_cvt_pk_bf16_f32 %0, %1, %2" : "=v"(d1) : "v"(xv[i][2]), "v"(xv[i][3]));
        int f = i * 1024 + tid * 4;
        int r = f >> 9, cc = f & 511;
        uiv2 dv = { d0, d1 };
        *(uiv2*)&xt[nxt][r][cc] = dv;
      }
    }

    // P1: wait for h(t): every wave polls all 32 flags
    {
      const int* fp = flags + (lane & 31);
      int v;
      do { v = ldflag<L>(fp); } while (v < t);
    }

    // P2: cooperative h staging loads (8 x dwordx4/thread = 32KB/WG, one round)
    const unsigned short* hb = hbuf + cur * (BB * HH);
    iv4 hreg[8];
#pragma unroll
    for (int rd = 0; rd < 8; ++rd)
      hreg[rd] = ldx4<L>(hb + rd * 2048 + tid * 8);

    // P3: x-side MFMAs from xt[cur] hide h-load latency; even/odd-K chains
    fv4 a0e = {0.f,0.f,0.f,0.f}, a0o = {0.f,0.f,0.f,0.f};
    fv4 a1e = {0.f,0.f,0.f,0.f}, a1o = {0.f,0.f,0.f,0.f};
#pragma unroll
    for (int kc = 0; kc < 16; kc += 2) {
      short8 xa0 = *(const short8*)&xt[cur][n][kc * 32 + q * 8];
      short8 xa1 = *(const short8*)&xt[cur][16 + n][kc * 32 + q * 8];
      short8 xb0 = *(const short8*)&xt[cur][n][(kc + 1) * 32 + q * 8];
      short8 xb1 = *(const short8*)&xt[cur][16 + n][(kc + 1) * 32 + q * 8];
      a0e = __builtin_amdgcn_mfma_f32_16x16x32_bf16(xa0, wxf[kc], a0e, 0, 0, 0);
      a1e = __builtin_amdgcn_mfma_f32_16x16x32_bf16(xa1, wxf[kc], a1e, 0, 0, 0);
      a0o = __builtin_amdgcn_mfma_f32_16x16x32_bf16(xb0, wxf[kc + 1], a0o, 0, 0, 0);
      a1o = __builtin_amdgcn_mfma_f32_16x16x32_bf16(xb1, wxf[kc + 1], a1o, 0, 0, 0);
    }

    // P4: only the 8 h loads are outstanding now -> plain vmcnt(0)
    asm volatile("s_waitcnt vmcnt(0)" ::: "memory");
    __builtin_amdgcn_sched_barrier(0);
#pragma unroll
    for (int rd = 0; rd < 8; ++rd) {
      int f = rd * 2048 + tid * 8;
      int r = f >> 9, cc = f & 511;
      *(iv4*)&hl[r][cc] = hreg[rd];
    }
    asm volatile("s_waitcnt lgkmcnt(0)" ::: "memory");
    asm volatile("s_barrier" ::: "memory");

    // P5: h-side MFMAs from LDS (same split chains), then combine
#pragma unroll
    for (int kc = 0; kc < 16; kc += 2) {
      short8 ha0 = *(const short8*)&hl[n][kc * 32 + q * 8];
      short8 ha1 = *(const short8*)&hl[16 + n][kc * 32 + q * 8];
      short8 hb0 = *(const short8*)&hl[n][(kc + 1) * 32 + q * 8];
      short8 hb1 = *(const short8*)&hl[16 + n][(kc + 1) * 32 + q * 8];
      a0e = __builtin_amdgcn_mfma_f32_16x16x32_bf16(ha0, whf[kc], a0e, 0, 0, 0);
      a1e = __builtin_amdgcn_mfma_f32_16x16x32_bf16(ha1, whf[kc], a1e, 0, 0, 0);
      a0o = __builtin_amdgcn_mfma_f32_16x16x32_bf16(hb0, whf[kc + 1], a0o, 0, 0, 0);
      a1o = __builtin_amdgcn_mfma_f32_16x16x32_bf16(hb1, whf[kc + 1], a1o, 0, 0, 0);
    }
    fv4 acc0 = a0e + a0o;
    fv4 acc1 = a1e + a1o;

    // P6: exchange gate preacts: D layout col=lane&15, row=quad*4+reg
#pragma unroll
    for (int r = 0; r < 4; ++r) {
      gl[w][q * 4 + r][n] = acc0[r];
      gl[w][16 + q * 4 + r][n] = acc1[r];
    }
    asm volatile("s_waitcnt lgkmcnt(0)" ::: "memory");
    asm volatile("s_barrier" ::: "memory");

    // P7: elementwise LSTM cell; h store at protocol scope
    float oo0, oo1;
    {
      fv2 gi = *(const fv2*)&gl[0][bE][jlE];
      fv2 gf = *(const fv2*)&gl[1][bE][jlE];
      fv2 gg = *(const fv2*)&gl[2][bE][jlE];
      fv2 go = *(const fv2*)&gl[3][bE][jlE];
      float oo[2];
#pragma unroll
      for (int e = 0; e < 2; ++e) {
        float ig = sigm(gi[e] + bias0[e]);
        float fg = sigm(gf[e] + bias1[e]);
        float gv = tanhfast(gg[e] + bias2[e]);
        float og = sigm(go[e] + bias3[e]);
        float cn = fg * c_st[e] + ig * gv;
        c_st[e] = cn;
        hv[e] = og * tanhfast(cn);
        oo[e] = og;
      }
      oo0 = oo[0]; oo1 = oo[1];
      unsigned hp;
      asm("v_cvt_pk_bf16_f32 %0, %1, %2" : "=v"(hp) : "v"(hv[0]), "v"(hv[1]));
      st32<L>(hbuf + nxt * (BB * HH) + bE * HH + j0 + jlE, hp);
    }

    // P8: drain h store (only outstanding op), barrier, release flag
    asm volatile("s_waitcnt vmcnt(0)" ::: "memory");
    asm volatile("s_barrier" ::: "memory");
    if (tid == 0) st32<L>(flags + wg, (unsigned)(t + 1));

    // P9: out store (cached) + x(t+2) prefetch — both OFF the release path
    {
      fv2 ov = {oo0, oo1};
      *(fv2*)(out + 32768 + (size_t)t * 16384 + bE * 512 + j0 + jlE) = ov;
    }
    {
      const float* xsrc = xs + (size_t)((t + 2 < TT) ? (t + 2) : (TT - 1)) * 16384;
#pragma unroll
      for (int i = 0; i < 16; ++i) {
        asm volatile("global_load_dwordx4 %0, %1, off"
                     : "=&v"(xv[i]) : "v"(xsrc + i * 1024 + tid * 4) : "memory");
      }
    }
  }

  // final h, c (f32)
  {
    fv2 hvv = {hv[0], hv[1]};
    fv2 cvv = {c_st[0], c_st[1]};
    *(fv2*)(out + bE * 512 + j0 + jlE) = hvv;
    *(fv2*)(out + 16384 + bE * 512 + j0 + jlE) = cvv;
  }
}

// ---- persistent scan with hang-free XCD self-colocation ----
__global__ __launch_bounds__(256, 1) void lstm_scan(
    const float* __restrict__ xs, const float* __restrict__ c0,
    const unsigned short* __restrict__ WhT, const unsigned short* __restrict__ WxT,
    const float* __restrict__ bsum,
    unsigned short* __restrict__ hbuf, int* __restrict__ flags,
    int* __restrict__ rankctr, int* __restrict__ xcc_pub,
    float* __restrict__ out)
{
  __shared__ unsigned short xt[2][BB][520];  // x bf16 ring, pad 8
  __shared__ unsigned short hl[BB][520];     // staged h(t) tile
  __shared__ float gl[4][BB][18];            // gate preacts exchange
  __shared__ int s_rank, s_mode;

  const int tid = threadIdx.x;

  // Rank claim: every block claims exactly once (no waiting -> no deadlock).
  // XCD0 residents claim first (bounded sleep bias) so ranks 0-31 colocate.
  if (tid == 0) {
    unsigned xcc;
    asm volatile("s_getreg_b32 %0, hwreg(HW_REG_XCC_ID)" : "=s"(xcc));
    xcc &= 15u;
    if (xcc != 0u)
      for (int i = 0; i < 8; ++i) __builtin_amdgcn_s_sleep(127);  // ~27us
    int r = __hip_atomic_fetch_add(rankctr, 1, __ATOMIC_RELAXED, __HIP_MEMORY_SCOPE_AGENT);
    s_rank = (r < NWG) ? r : -1;
    if (r < NWG) {
      int xi = (int)xcc;
      asm volatile("global_store_dword %0, %1, off sc0 sc1\n\ts_waitcnt vmcnt(0)"
                   :: "v"(xcc_pub + r), "v"(xi) : "memory");
    }
  }
  __syncthreads();
  const int wg = s_rank;
  if (wg < 0) return;

  // Homogeneity handshake (terminates: all 32 ranks are claimed by live
  // blocks that publish before polling). allsame -> L2-local protocol.
  if (tid < 64) {
    const int* pp = xcc_pub + (tid & 31);
    int pv;
    do {
      asm volatile("global_load_dword %0, %1, off sc0 sc1\n\ts_waitcnt vmcnt(0)"
                   : "=v"(pv) : "v"(pp) : "memory");
    } while (pv < 0);
    int p0 = __shfl(pv, 0);
    unsigned long long bal = __ballot(pv == p0);
    if (tid == 0) s_mode = (bal == ~0ull) ? 1 : 0;
  }
  __syncthreads();

  if (s_mode)
    run_scan<true >(wg, tid, xs, c0, WhT, WxT, bsum, hbuf, flags, out, xt, hl, gl);
  else
    run_scan<false>(wg, tid, xs, c0, WhT, WxT, bsum, hbuf, flags, out, xt, hl, gl);
}

extern "C" void kernel_launch(void* const* d_in, const int* in_sizes, int n_in,
                              void* d_out, int out_size, void* d_ws, size_t ws_size,
                              hipStream_t stream) {
  (void)in_sizes; (void)n_in; (void)out_size;
  const float* h0  = (const float*)d_in[0];
  const float* c0  = (const float*)d_in[1];
  const float* xs  = (const float*)d_in[2];
  const float* Wii = (const float*)d_in[3];
  const float* bii = (const float*)d_in[4];
  const float* Whi = (const float*)d_in[5];
  const float* bhi = (const float*)d_in[6];
  const float* Wif = (const float*)d_in[7];
  const float* bif = (const float*)d_in[8];
  const float* Whf = (const float*)d_in[9];
  const float* bhf = (const float*)d_in[10];
  const float* Wig = (const float*)d_in[11];
  const float* big = (const float*)d_in[12];
  const float* Whg = (const float*)d_in[13];
  const float* bhg = (const float*)d_in[14];
  const float* Wio = (const float*)d_in[15];
  const float* bio = (const float*)d_in[16];
  const float* Who = (const float*)d_in[17];
  const float* bho = (const float*)d_in[18];

  // ws: WhT 2MB | WxT 2MB | bsum 8KB | hbuf 64KB | flags 128B | rankctr | xcc_pub
  char* ws = (char*)d_ws;
  unsigned short* WhT  = (unsigned short*)ws;
  unsigned short* WxT  = (unsigned short*)(ws + (2u << 20));
  float*          bsum = (float*)(ws + (4u << 20));
  unsigned short* hbuf = (unsigned short*)(ws + (4u << 20) + 8192);
  const size_t F = (4u << 20) + 8192 + 65536;
  int* flags   = (int*)(ws + F);
  int* rankctr = (int*)(ws + F + 128);
  int* xcc_pub = (int*)(ws + F + 256);
  if (ws_size < F + 512) return;  // visible failure if ws too small

  const int total = 2048 * 512 + 2048 + 16384 + NWG + 1 + 64;
  pack_kernel<<<(total + 255) / 256, 256, 0, stream>>>(
      h0, Wii, bii, Whi, bhi, Wif, bif, Whf, bhf,
      Wig, big, Whg, bhg, Wio, bio, Who, bho,
      WhT, WxT, bsum, hbuf, flags, rankctr, xcc_pub);
  lstm_scan<<<512, 256, 0, stream>>>(xs, c0, WhT, WxT, bsum, hbuf, flags,
                                     rankctr, xcc_pub, (float*)d_out);
}